// Round 12
// baseline (377.970 us; speedup 1.0000x reference)
//
#include <hip/hip_runtime.h>
#include <hip/hip_bf16.h>
#include <hip/hip_fp16.h>

// 5-layer GCN: widths 128 -> 128/64/32/16/8, N=100000 nodes, E=1600000 edges.
// R22: DIAGNOSTIC SPLIT + LAST FP16 BOUNDARIES — top-5 is saturated by L1
//      aggrh instances (~66 us, at the ~6.2 TB/s gather byte-floor), hiding
//      ~150 us of unattributed time. L1 aggr split into two 2-slice
//      dispatches (identical semantics) so next profile reveals the second
//      tier. Also: L3->L4 and L4->L5 boundaries go fp16 (aggrh L3 ->
//      [n][32]h; aggr16h -> [n][16]h; VALU gemm gains fp16 row-major input)
//      — ~20 MB saved, same rounding class as R19/R20 (absmax-insensitive).
// R20/21: fp16 L4/L5 tail + k_bscan fold. 380 -> 373.7.
// R19: fp16 layer boundaries L1->L2->L3. R18: bucket+counting-sort build.
// R17: MFMA fp16 GEMM L1-3. R15: fp16 gather payload, 32-feat slices.

#define LDSE16  2048  // aggrh: staged edge indices (8 KB), 64 nodes/block
#define LDSE16B 3072  // aggr16h: staged edge indices (12 KB), 128 nodes/block
#define LDSE8H  6144  // aggr8h: staged edge indices (24 KB), 256 nodes/block
#define PCHUNK 4096   // k_bucket: edges per block
#define BNODES 512    // nodes per bucket
#define MAXBUK 256    // max buckets (N <= 131072)

typedef float floatx4 __attribute__((ext_vector_type(4)));
typedef _Float16 f16x4 __attribute__((ext_vector_type(4)));
typedef _Float16 f16x8 __attribute__((ext_vector_type(8)));

// ---------------- chunked bucket partition (bucket = dst/512) ----------------
__global__ __launch_bounds__(256) void k_bucket(const int* __restrict__ src,
                                                const int* __restrict__ dst,
                                                int2* __restrict__ pairs,
                                                int* __restrict__ bcnt,
                                                int E, int nbk, int CAP) {
    __shared__ int  hist[MAXBUK], pre[MAXBUK], cur[MAXBUK], gbase[MAXBUK], tmp[MAXBUK];
    __shared__ int2 arena[PCHUNK];              // 32 KB
    const int tid = threadIdx.x;
    const int e0  = blockIdx.x * PCHUNK;
    const int m   = (E - e0 < PCHUNK) ? (E - e0) : PCHUNK;

    hist[tid] = 0;
    __syncthreads();

    int dl[PCHUNK / 256], sl[PCHUNK / 256], rl[PCHUNK / 256];
#pragma unroll
    for (int j = 0; j < PCHUNK / 256; ++j) {
        int i = j * 256 + tid;
        rl[j] = -1;
        if (i < m) {
            dl[j] = __builtin_nontemporal_load(&dst[e0 + i]);
            sl[j] = __builtin_nontemporal_load(&src[e0 + i]);
            rl[j] = dl[j] >> 9;                 // dst / BNODES
            atomicAdd(&hist[rl[j]], 1);
        }
    }
    __syncthreads();
    // exclusive scan of hist[256]
    int v = hist[tid];
    tmp[tid] = v;
    __syncthreads();
    for (int off = 1; off < MAXBUK; off <<= 1) {
        int t = (tid >= off) ? tmp[tid - off] : 0;
        __syncthreads();
        tmp[tid] += t;
        __syncthreads();
    }
    pre[tid] = tmp[tid] - v;
    cur[tid] = 0;
    __syncthreads();
#pragma unroll
    for (int j = 0; j < PCHUNK / 256; ++j) {
        if (rl[j] >= 0) {
            int slot = pre[rl[j]] + atomicAdd(&cur[rl[j]], 1);
            arena[slot] = make_int2(dl[j], sl[j]);
        }
    }
    __syncthreads();
    if (tid < nbk && hist[tid] > 0) gbase[tid] = atomicAdd(&bcnt[tid], hist[tid]);
    __syncthreads();
    // flush: one wave per bucket, coalesced runs
    const int wave = tid >> 6, lane = tid & 63;
    for (int r = wave; r < nbk; r += 4) {
        int cnt = hist[r];
        if (cnt == 0) continue;
        int b0 = pre[r], g = gbase[r];
        for (int j = lane; j < cnt; j += 64)
            pairs[(size_t)r * CAP + g + j] = arena[b0 + j];
    }
}

// ---------------- per-bucket LDS counting sort -> CSR + deg/dinv/offsets ----
// Derives its own base via a 256-wide prefix of bcnt (bscan folded in).
__global__ __launch_bounds__(256) void k_sortfill(const int2* __restrict__ pairs,
                                                  const int* __restrict__ bcnt,
                                                  int* __restrict__ csr_src,
                                                  int* __restrict__ offsets,
                                                  float* __restrict__ dinv,
                                                  int n, int E, int nbk, int CAP) {
    __shared__ int hist[BNODES], lofs[BNODES], cur[BNODES], tmp[256];
    __shared__ int sbase;
    const int r    = blockIdx.x;
    const int tid  = threadIdx.x;
    const int node0 = r * BNODES;
    const int2* p = pairs + (size_t)r * CAP;

    // bucket-prefix: base = sum of bcnt[0..r-1]
    int bv = (tid < nbk) ? bcnt[tid] : 0;
    tmp[tid] = bv;
    __syncthreads();
    for (int off = 1; off < 256; off <<= 1) {
        int t = (tid >= off) ? tmp[tid - off] : 0;
        __syncthreads();
        tmp[tid] += t;
        __syncthreads();
    }
    if (tid == r) sbase = tmp[r] - bv;          // exclusive prefix at r
    if (r == nbk - 1 && tid == 0) offsets[n] = E;
    __syncthreads();
    const int m    = bcnt[r];
    const int base = sbase;

    for (int l = tid; l < BNODES; l += 256) hist[l] = 0;
    __syncthreads();
    for (int i = tid; i < m; i += 256)
        atomicAdd(&hist[p[i].x - node0], 1);
    __syncthreads();
    // exclusive scan of hist[512] with 256 threads (2 elems/thread)
    int a = hist[2 * tid], b = hist[2 * tid + 1];
    int s = a + b;
    tmp[tid] = s;
    __syncthreads();
    for (int off = 1; off < 256; off <<= 1) {
        int t = (tid >= off) ? tmp[tid - off] : 0;
        __syncthreads();
        tmp[tid] += t;
        __syncthreads();
    }
    int exc = tmp[tid] - s;
    lofs[2 * tid]     = exc;
    lofs[2 * tid + 1] = exc + a;
    cur[2 * tid] = 0;
    cur[2 * tid + 1] = 0;
    __syncthreads();
    // place: all global writes land in csr_src[base .. base+m) (32 KB window)
    for (int i = tid; i < m; i += 256) {
        int2 e = p[i];
        int l = e.x - node0;
        int pos = lofs[l] + atomicAdd(&cur[l], 1);
        csr_src[base + pos] = e.y;
    }
    for (int l = tid; l < BNODES; l += 256) {
        int node = node0 + l;
        if (node < n) {
            offsets[node] = base + lofs[l];
            dinv[node]    = rsqrtf((float)(hist[l] + 1));   // +1 self loop
        }
    }
}

// ---------------- MFMA fp16 GEMM (layers 1-3; fp16 blocked32 output) -------
// 512 threads = 4 waves; 128 nodes/block; wave w owns nodes 16w..16w+15.
// A staged fp16 LDS [node][k] pitch AP=KC+8; W^T staged fp16 [fo][k].
// H16IN: input fp16 blocked32 [fi/32][n][32]h; else fp32 row-major.
// mfma_f32_16x16x32_f16 frag: A row=lane&15, k=(lane>>4)*4+(r&3)+16*(r>>2);
// B col=lane&15 same k; D col=lane&15, row=(lane>>4)*4+r.
template <int FIN, int FOUT, bool H16IN>
__global__ __launch_bounds__(512) void k_mgemm(const float* __restrict__ x,
                                               const float* __restrict__ W,
                                               const float* __restrict__ dinv,
                                               _Float16* __restrict__ g, int n) {
    constexpr int KC  = (FIN < 64) ? FIN : 64;
    constexpr int NKQ = KC / 4;
    constexpr int AP  = KC + 8;              // pitch in halfs (16-B aligned rows)
    constexpr int NT  = FOUT / 16;
    __shared__ _Float16 As[128 * AP];
    __shared__ _Float16 Ws[FOUT * AP];
    __shared__ float dv[128];

    const int tid  = threadIdx.x;
    const int wave = tid >> 6;
    const int lane = tid & 63;
    const int m0   = blockIdx.x * 128;

    if (tid < 128) dv[tid] = (m0 + tid < n) ? dinv[m0 + tid] : 0.f;

    floatx4 acc[NT];
#pragma unroll
    for (int t = 0; t < NT; ++t) acc[t] = (floatx4)(0.f);

    for (int kc0 = 0; kc0 < FIN; kc0 += KC) {
        __syncthreads();
        if constexpr (H16IN) {
            const _Float16* xh = reinterpret_cast<const _Float16*>(x);
            constexpr int NC8 = KC / 8;
            for (int s = tid; s < 128 * NC8; s += 512) {
                int node = s / NC8, c8 = s % NC8;
                int gn = m0 + node, f0 = kc0 + c8 * 8;
                f16x8 h = (f16x8)(_Float16)0;
                if (gn < n)
                    h = *reinterpret_cast<const f16x8*>(
                        &xh[((size_t)(f0 >> 5) * n + gn) * 32 + (f0 & 31)]);
                *reinterpret_cast<f16x8*>(&As[node * AP + c8 * 8]) = h;
            }
        } else {
            const floatx4* x4 = reinterpret_cast<const floatx4*>(x);
            for (int s = tid; s < 128 * NKQ; s += 512) {
                int node = s / NKQ, kq = s % NKQ;
                int gn = m0 + node, gslot = kc0 / 4 + kq;
                floatx4 v = (floatx4)(0.f);
                if (gn < n)
                    v = __builtin_nontemporal_load(&x4[(size_t)gn * (FIN / 4) + gslot]);
                f16x4 h = {(_Float16)v.x, (_Float16)v.y, (_Float16)v.z, (_Float16)v.w};
                *reinterpret_cast<f16x4*>(&As[node * AP + kq * 4]) = h;
            }
        }
        // stage W^T: fp16 [fo][k]
        for (int s = tid; s < FOUT * NKQ; s += 512) {
            int fo = s % FOUT, kq = s / FOUT;
            int k = kc0 + kq * 4;
            f16x4 h = {(_Float16)W[(k + 0) * FOUT + fo], (_Float16)W[(k + 1) * FOUT + fo],
                       (_Float16)W[(k + 2) * FOUT + fo], (_Float16)W[(k + 3) * FOUT + fo]};
            *reinterpret_cast<f16x4*>(&Ws[fo * AP + kq * 4]) = h;
        }
        __syncthreads();
#pragma unroll
        for (int kk = 0; kk < KC / 32; ++kk) {
            const int ka = kk * 32 + ((lane >> 4) << 2);
            const _Float16* ap = &As[(wave * 16 + (lane & 15)) * AP + ka];
            f16x4 alo = *reinterpret_cast<const f16x4*>(ap);
            f16x4 ahi = *reinterpret_cast<const f16x4*>(ap + 16);
            f16x8 a = {alo[0], alo[1], alo[2], alo[3], ahi[0], ahi[1], ahi[2], ahi[3]};
#pragma unroll
            for (int t = 0; t < NT; ++t) {
                const _Float16* bp = &Ws[(t * 16 + (lane & 15)) * AP + ka];
                f16x4 blo = *reinterpret_cast<const f16x4*>(bp);
                f16x4 bhi = *reinterpret_cast<const f16x4*>(bp + 16);
                f16x8 b = {blo[0], blo[1], blo[2], blo[3], bhi[0], bhi[1], bhi[2], bhi[3]};
                acc[t] = __builtin_amdgcn_mfma_f32_16x16x32_f16(a, b, acc[t], 0, 0, 0);
            }
        }
    }

    const int i0 = (lane >> 4) << 2;
#pragma unroll
    for (int r = 0; r < 4; ++r) {
        int nl = wave * 16 + i0 + r;
        int node = m0 + nl;
        if (node < n) {
            float d = dv[nl];
#pragma unroll
            for (int t = 0; t < NT; ++t) {
                int fo = t * 16 + (lane & 15);
                g[((size_t)(fo >> 5) * n + node) * 32 + (fo & 31)] = (_Float16)(acc[t][r] * d);
            }
        }
    }
}

// ---------------- register-blocked VALU GEMM (layers 4-5) ----------------
// Input: fp16 row-major [n][FIN]h. Output: fp16 row-major [n][FOUT]h.
template <int FIN, int FOUT, int NR, int NC>
__global__ __launch_bounds__(256) void k_gemm(const _Float16* __restrict__ xh,
                                              const float* __restrict__ W,
                                              const float* __restrict__ dinv,
                                              _Float16* __restrict__ gh, int n) {
    constexpr int NFG = FOUT / NC;            // fo-groups per block
    constexpr int M   = NR * (256 / NFG);     // nodes per block
    constexpr int KC  = (FIN < 32) ? FIN : 32;
    constexpr int MP  = M + 4;
    constexpr int WP  = KC * NC + 4;          // pitch in dwords, %32 == 4
    __shared__ float Wl[NFG * WP];
    __shared__ float xt[KC * MP];

    const int tid = threadIdx.x;
    const int fg  = tid % NFG;
    const int mg  = tid / NFG;
    const int m0  = blockIdx.x * M;

    float acc[NR][NC];
#pragma unroll
    for (int i = 0; i < NR; ++i)
#pragma unroll
        for (int j = 0; j < NC; ++j) acc[i][j] = 0.f;

    for (int kc0 = 0; kc0 < FIN; kc0 += KC) {
        __syncthreads();
        for (int idx = tid; idx < KC * FOUT; idx += 256) {
            int k  = idx / FOUT;
            int fo = idx % FOUT;
            Wl[(fo / NC) * WP + k * NC + (fo % NC)] = W[(kc0 + k) * FOUT + fo];
        }
        constexpr int SL8 = KC / 8;             // f16x8 slots per node per chunk
        for (int s = tid; s < M * SL8; s += 256) {
            int ml = s / SL8;
            int c8 = s % SL8;
            int gn = m0 + ml;
            f16x8 h = (f16x8)(_Float16)0;
            if (gn < n)
                h = *reinterpret_cast<const f16x8*>(&xh[(size_t)gn * FIN + kc0 + c8 * 8]);
#pragma unroll
            for (int j = 0; j < 8; ++j)
                xt[(c8 * 8 + j) * MP + ml] = (float)h[j];
        }
        __syncthreads();
#pragma unroll 4
        for (int k = 0; k < KC; ++k) {
            float xr[NR], wr[NC];
#pragma unroll
            for (int p = 0; p < NR / 4; ++p) {
                float4 v = *reinterpret_cast<const float4*>(&xt[k * MP + mg * NR + p * 4]);
                xr[p * 4 + 0] = v.x; xr[p * 4 + 1] = v.y;
                xr[p * 4 + 2] = v.z; xr[p * 4 + 3] = v.w;
            }
#pragma unroll
            for (int p = 0; p < NC / 4; ++p) {
                float4 v = *reinterpret_cast<const float4*>(&Wl[fg * WP + k * NC + p * 4]);
                wr[p * 4 + 0] = v.x; wr[p * 4 + 1] = v.y;
                wr[p * 4 + 2] = v.z; wr[p * 4 + 3] = v.w;
            }
#pragma unroll
            for (int i = 0; i < NR; ++i)
#pragma unroll
                for (int j = 0; j < NC; ++j) acc[i][j] += xr[i] * wr[j];
        }
    }

#pragma unroll
    for (int i = 0; i < NR; ++i) {
        int gn = m0 + mg * NR + i;
        if (gn < n) {
            float d = dinv[gn];
            f16x4 o;
#pragma unroll
            for (int j = 0; j < NC; ++j) o[j] = (_Float16)(acc[i][j] * d);
            *reinterpret_cast<f16x4*>(&gh[(size_t)gn * FOUT + fg * NC]) = o;
        }
    }
}

// accumulate 8 fp16 feats (one float4 = 4 half2) into 8 fp32 accumulators
#define ACCUM8(A, v) {                                                        \
    union { float4 f; __half2 h[4]; } u_; u_.f = (v);                         \
    _Pragma("unroll")                                                         \
    for (int j_ = 0; j_ < 4; ++j_) {                                          \
        float2 f_ = __half22float2(u_.h[j_]);                                 \
        A[2 * j_] += f_.x; A[2 * j_ + 1] += f_.y;                             \
    } }

// ---------------- fp16 32-feat-slice CSR aggregation (layers 1-3) ----------
// g fp16 blocked32 [f/32][N][32]h: 64 B/node/slice, 4 lanes/node, 8 loads in
// flight. fp32 accumulation. H16OUT -> fp16 blocked32; else fp32 blocked16.
// sl0: slice offset (lets one layer's slices split across dispatches).
template <bool H16OUT>
__global__ __launch_bounds__(256) void k_aggrh(const float4* __restrict__ gh,
                                               const int* __restrict__ offsets,
                                               const int* __restrict__ csr_src,
                                               const float* __restrict__ dinv,
                                               const float* __restrict__ bias,
                                               float4* __restrict__ outb,
                                               int n, int nsl, int sl0) {
    __shared__ int eidx[LDSE16];
    const int sl     = sl0 + blockIdx.x % nsl;
    const int nb     = blockIdx.x / nsl;
    const int node0  = nb * 64;
    const int nodeHi = (node0 + 64 < n) ? node0 + 64 : n;
    const int node   = node0 + (threadIdx.x >> 2);
    const int q      = threadIdx.x & 3;

    const int eS = offsets[node0];
    const int eE = offsets[nodeHi];
    const int C  = eE - eS;
    const bool useLds = (C <= LDSE16);

    const bool alive = (node < n);
    int e0 = 0, e1 = 0;
    float dnode = 0.f;
    const float4* gs = gh + (size_t)sl * n * 4;   // 4 float4 (64 B) per node
    float A[8], B[8];
#pragma unroll
    for (int j = 0; j < 8; ++j) { A[j] = 0.f; B[j] = 0.f; }
    if (alive) {
        e0 = offsets[node];
        e1 = offsets[node + 1];
        dnode = dinv[node];
        float4 vs = gs[(size_t)node * 4 + q];     // self-loop term
        ACCUM8(A, vs);
    }

    if (useLds) {
        for (int i = threadIdx.x; i < C; i += 256)
            eidx[i] = __builtin_nontemporal_load(&csr_src[eS + i]);
    }
    __syncthreads();
    if (!alive) return;

    const int m = e1 - e0;
    int i = 0;
    if (useLds) {
        const int le = e0 - eS;
        for (; i + 8 <= m; i += 8) {
            int s0 = eidx[le + i + 0], s1 = eidx[le + i + 1];
            int s2 = eidx[le + i + 2], s3 = eidx[le + i + 3];
            int s4 = eidx[le + i + 4], s5 = eidx[le + i + 5];
            int s6 = eidx[le + i + 6], s7 = eidx[le + i + 7];
            float4 v0 = gs[(size_t)s0 * 4 + q], v1 = gs[(size_t)s1 * 4 + q];
            float4 v2 = gs[(size_t)s2 * 4 + q], v3 = gs[(size_t)s3 * 4 + q];
            float4 v4 = gs[(size_t)s4 * 4 + q], v5 = gs[(size_t)s5 * 4 + q];
            float4 v6 = gs[(size_t)s6 * 4 + q], v7 = gs[(size_t)s7 * 4 + q];
            ACCUM8(A, v0); ACCUM8(B, v1); ACCUM8(A, v2); ACCUM8(B, v3);
            ACCUM8(A, v4); ACCUM8(B, v5); ACCUM8(A, v6); ACCUM8(B, v7);
        }
        for (; i + 4 <= m; i += 4) {
            int s0 = eidx[le + i + 0], s1 = eidx[le + i + 1];
            int s2 = eidx[le + i + 2], s3 = eidx[le + i + 3];
            float4 v0 = gs[(size_t)s0 * 4 + q], v1 = gs[(size_t)s1 * 4 + q];
            float4 v2 = gs[(size_t)s2 * 4 + q], v3 = gs[(size_t)s3 * 4 + q];
            ACCUM8(A, v0); ACCUM8(B, v1); ACCUM8(A, v2); ACCUM8(B, v3);
        }
        for (; i < m; ++i) {
            float4 v = gs[(size_t)eidx[le + i] * 4 + q];
            ACCUM8(A, v);
        }
    } else {
        for (; i + 4 <= m; i += 4) {
            int s0 = csr_src[e0 + i + 0], s1 = csr_src[e0 + i + 1];
            int s2 = csr_src[e0 + i + 2], s3 = csr_src[e0 + i + 3];
            float4 v0 = gs[(size_t)s0 * 4 + q], v1 = gs[(size_t)s1 * 4 + q];
            float4 v2 = gs[(size_t)s2 * 4 + q], v3 = gs[(size_t)s3 * 4 + q];
            ACCUM8(A, v0); ACCUM8(B, v1); ACCUM8(A, v2); ACCUM8(B, v3);
        }
        for (; i < m; ++i) {
            float4 v = gs[(size_t)csr_src[e0 + i] * 4 + q];
            ACCUM8(A, v);
        }
    }

    const float* bf = bias + sl * 32 + q * 8;
    float r[8];
#pragma unroll
    for (int j = 0; j < 8; ++j)
        r[j] = fmaxf(dnode * (A[j] + B[j]) + bf[j], 0.f);

    if constexpr (H16OUT) {
        f16x8 o;
#pragma unroll
        for (int j = 0; j < 8; ++j) o[j] = (_Float16)r[j];
        _Float16* oh = reinterpret_cast<_Float16*>(outb);
        __builtin_nontemporal_store(
            o, reinterpret_cast<f16x8*>(&oh[((size_t)sl * n + node) * 32 + q * 8]));
    } else {
        floatx4 r0 = {r[0], r[1], r[2], r[3]};
        floatx4 r1 = {r[4], r[5], r[6], r[7]};
        floatx4* ob = reinterpret_cast<floatx4*>(outb);
        size_t base = ((size_t)(sl * 2 + (q >> 1)) * n + node) * 4 + (q & 1) * 2;
        __builtin_nontemporal_store(r0, &ob[base + 0]);
        __builtin_nontemporal_store(r1, &ob[base + 1]);
    }
}

// ---------------- fp16 16-feat CSR aggregation (layer 4) -------------------
// g fp16 row-major [n][16]h (32 B/node); 2 lanes/node, 128 nodes/block.
// fp32 accumulation; writes fp16 row-major [n][16]h xbuf (for the L5 gemm).
__global__ __launch_bounds__(256) void k_aggr16h(const _Float16* __restrict__ gh,
                                                 const int* __restrict__ offsets,
                                                 const int* __restrict__ csr_src,
                                                 const float* __restrict__ dinv,
                                                 const float* __restrict__ bias,
                                                 _Float16* __restrict__ outh, int n) {
    __shared__ int eidx[LDSE16B];
    const int node0  = blockIdx.x * 128;
    const int nodeHi = (node0 + 128 < n) ? node0 + 128 : n;
    const int node   = node0 + (threadIdx.x >> 1);
    const int h      = threadIdx.x & 1;

    const int eS = offsets[node0];
    const int eE = offsets[nodeHi];
    const int C  = eE - eS;
    const bool useLds = (C <= LDSE16B);

    const bool alive = (node < n);
    int e0 = 0, e1 = 0;
    float dnode = 0.f;
    float A[8], B[8];
#pragma unroll
    for (int j = 0; j < 8; ++j) { A[j] = 0.f; B[j] = 0.f; }
    if (alive) {
        e0 = offsets[node];
        e1 = offsets[node + 1];
        dnode = dinv[node];
        f16x8 vs = *reinterpret_cast<const f16x8*>(&gh[(size_t)node * 16 + h * 8]);
#pragma unroll
        for (int j = 0; j < 8; ++j) A[j] += (float)vs[j];
    }

    if (useLds) {
        for (int i = threadIdx.x; i < C; i += 256)
            eidx[i] = __builtin_nontemporal_load(&csr_src[eS + i]);
    }
    __syncthreads();
    if (!alive) return;

    const int m = e1 - e0;
    int i = 0;
    if (useLds) {
        const int le = e0 - eS;
        for (; i + 4 <= m; i += 4) {
            int s0 = eidx[le + i + 0], s1 = eidx[le + i + 1];
            int s2 = eidx[le + i + 2], s3 = eidx[le + i + 3];
            f16x8 v0 = *reinterpret_cast<const f16x8*>(&gh[(size_t)s0 * 16 + h * 8]);
            f16x8 v1 = *reinterpret_cast<const f16x8*>(&gh[(size_t)s1 * 16 + h * 8]);
            f16x8 v2 = *reinterpret_cast<const f16x8*>(&gh[(size_t)s2 * 16 + h * 8]);
            f16x8 v3 = *reinterpret_cast<const f16x8*>(&gh[(size_t)s3 * 16 + h * 8]);
#pragma unroll
            for (int j = 0; j < 8; ++j) {
                A[j] += (float)v0[j] + (float)v2[j];
                B[j] += (float)v1[j] + (float)v3[j];
            }
        }
        for (; i < m; ++i) {
            f16x8 v = *reinterpret_cast<const f16x8*>(
                &gh[(size_t)eidx[le + i] * 16 + h * 8]);
#pragma unroll
            for (int j = 0; j < 8; ++j) A[j] += (float)v[j];
        }
    } else {
        for (; i < m; ++i) {
            f16x8 v = *reinterpret_cast<const f16x8*>(
                &gh[(size_t)csr_src[e0 + i] * 16 + h * 8]);
#pragma unroll
            for (int j = 0; j < 8; ++j) A[j] += (float)v[j];
        }
    }

    const float* bf = bias + h * 8;
    f16x8 o;
#pragma unroll
    for (int j = 0; j < 8; ++j)
        o[j] = (_Float16)fmaxf(dnode * (A[j] + B[j]) + bf[j], 0.f);
    __builtin_nontemporal_store(
        o, reinterpret_cast<f16x8*>(&outh[(size_t)node * 16 + h * 8]));
}

// ---------------- fp16 8-feat CSR aggregation (layer 5, writes d_out) ------
// g fp16 row-major [n][8]h (16 B/node); 1 lane/node (one f16x8 per edge),
// 256 nodes/block. fp32 accumulation; writes fp32 [n][8] d_out.
__global__ __launch_bounds__(256) void k_aggr8h(const _Float16* __restrict__ gh,
                                                const int* __restrict__ offsets,
                                                const int* __restrict__ csr_src,
                                                const float* __restrict__ dinv,
                                                const float* __restrict__ bias,
                                                float4* __restrict__ outb, int n) {
    __shared__ int eidx[LDSE8H];
    const int node0  = blockIdx.x * 256;
    const int nodeHi = (node0 + 256 < n) ? node0 + 256 : n;
    const int node   = node0 + threadIdx.x;

    const int eS = offsets[node0];
    const int eE = offsets[nodeHi];
    const int C  = eE - eS;
    const bool useLds = (C <= LDSE8H);

    const bool alive = (node < n);
    int e0 = 0, e1 = 0;
    float dnode = 0.f;
    float A[8], B[8];
#pragma unroll
    for (int j = 0; j < 8; ++j) { A[j] = 0.f; B[j] = 0.f; }
    if (alive) {
        e0 = offsets[node];
        e1 = offsets[node + 1];
        dnode = dinv[node];
        f16x8 vs = *reinterpret_cast<const f16x8*>(&gh[(size_t)node * 8]);
#pragma unroll
        for (int j = 0; j < 8; ++j) A[j] += (float)vs[j];
    }

    if (useLds) {
        for (int i = threadIdx.x; i < C; i += 256)
            eidx[i] = __builtin_nontemporal_load(&csr_src[eS + i]);
    }
    __syncthreads();
    if (!alive) return;

    const int m = e1 - e0;
    int i = 0;
    if (useLds) {
        const int le = e0 - eS;
        for (; i + 4 <= m; i += 4) {
            int s0 = eidx[le + i + 0], s1 = eidx[le + i + 1];
            int s2 = eidx[le + i + 2], s3 = eidx[le + i + 3];
            f16x8 v0 = *reinterpret_cast<const f16x8*>(&gh[(size_t)s0 * 8]);
            f16x8 v1 = *reinterpret_cast<const f16x8*>(&gh[(size_t)s1 * 8]);
            f16x8 v2 = *reinterpret_cast<const f16x8*>(&gh[(size_t)s2 * 8]);
            f16x8 v3 = *reinterpret_cast<const f16x8*>(&gh[(size_t)s3 * 8]);
#pragma unroll
            for (int j = 0; j < 8; ++j) {
                A[j] += (float)v0[j] + (float)v2[j];
                B[j] += (float)v1[j] + (float)v3[j];
            }
        }
        for (; i < m; ++i) {
            f16x8 v = *reinterpret_cast<const f16x8*>(&gh[(size_t)eidx[le + i] * 8]);
#pragma unroll
            for (int j = 0; j < 8; ++j) A[j] += (float)v[j];
        }
    } else {
        for (; i < m; ++i) {
            f16x8 v = *reinterpret_cast<const f16x8*>(&gh[(size_t)csr_src[e0 + i] * 8]);
#pragma unroll
            for (int j = 0; j < 8; ++j) A[j] += (float)v[j];
        }
    }

    floatx4 r0, r1;
    r0.x = fmaxf(dnode * (A[0] + B[0]) + bias[0], 0.f);
    r0.y = fmaxf(dnode * (A[1] + B[1]) + bias[1], 0.f);
    r0.z = fmaxf(dnode * (A[2] + B[2]) + bias[2], 0.f);
    r0.w = fmaxf(dnode * (A[3] + B[3]) + bias[3], 0.f);
    r1.x = fmaxf(dnode * (A[4] + B[4]) + bias[4], 0.f);
    r1.y = fmaxf(dnode * (A[5] + B[5]) + bias[5], 0.f);
    r1.z = fmaxf(dnode * (A[6] + B[6]) + bias[6], 0.f);
    r1.w = fmaxf(dnode * (A[7] + B[7]) + bias[7], 0.f);
    floatx4* ob = reinterpret_cast<floatx4*>(outb);
    __builtin_nontemporal_store(r0, &ob[(size_t)node * 2 + 0]);
    __builtin_nontemporal_store(r1, &ob[(size_t)node * 2 + 1]);
}

extern "C" void kernel_launch(void* const* d_in, const int* in_sizes, int n_in,
                              void* d_out, int out_size, void* d_ws, size_t ws_size,
                              hipStream_t stream) {
    const int N = in_sizes[0] / 128;
    const int E = in_sizes[1] / 2;
    const int nbk = (N + BNODES - 1) / BNODES;            // 196 buckets
    const int avg = (E + nbk - 1) / nbk;
    const int CAP = avg + avg / 4 + 512;                  // ~11+ sigma headroom

    const float* x   = (const float*)d_in[0];
    const int*   ei  = (const int*)d_in[1];
    const int*   src = ei;
    const int*   dst = ei + E;
    const float* W1 = (const float*)d_in[2],  *b1 = (const float*)d_in[3];
    const float* W2 = (const float*)d_in[4],  *b2 = (const float*)d_in[5];
    const float* W3 = (const float*)d_in[6],  *b3 = (const float*)d_in[7];
    const float* W4 = (const float*)d_in[8],  *b4 = (const float*)d_in[9];
    const float* W5 = (const float*)d_in[10], *b5 = (const float*)d_in[11];
    float* out = (float*)d_out;

    size_t off = 0;
    auto alloc = [&](size_t bytes) {
        void* p = (char*)d_ws + off;
        off += (bytes + 255) & ~(size_t)255;
        return p;
    };
    int*   offsets = (int*)alloc((size_t)(N + 1) * 4);
    float* dinv    = (float*)alloc((size_t)N * 4);
    int*   csr_src = (int*)alloc((size_t)E * 4);
    int*   bcnt    = (int*)alloc(MAXBUK * 4);
    int2*  pairs   = (int2*)alloc((size_t)nbk * CAP * 8);
    float* g       = (float*)alloc((size_t)N * 128 * 4);
    float* xbuf    = (float*)alloc((size_t)N * 128 * 4);

    (void)hipMemsetAsync(bcnt, 0, MAXBUK * 4, stream);

    const int TB = 256;
    int nb16  = (N + 63) / 64;       // aggrh: 64 nodes per block
    int nb128 = (N + 127) / 128;     // aggr16h / mgemm: 128 nodes per block
    int nb256 = (N + 255) / 256;     // aggr8h: 256 nodes per block
    int nch   = (E + PCHUNK - 1) / PCHUNK;

    k_bucket<<<nch, TB, 0, stream>>>(src, dst, pairs, bcnt, E, nbk, CAP);
    k_sortfill<<<nbk, TB, 0, stream>>>(pairs, bcnt, csr_src, offsets, dinv, N, E, nbk, CAP);

    const float4* g4  = (const float4*)g;
    float4*       xb4 = (float4*)xbuf;
    _Float16*     gh  = (_Float16*)g;
    _Float16*     xbh = (_Float16*)xbuf;

    // Layer 1: 128 -> 128  (MFMA fp16, fp32 row-major in; fp16 g, 4 slice32s;
    //                       aggr split into TWO 2-slice dispatches — diagnostic)
    k_mgemm<128, 128, false><<<nb128, 512, 0, stream>>>(x, W1, dinv, gh, N);
    k_aggrh<true><<<nb16 * 2, TB, 0, stream>>>(g4, offsets, csr_src, dinv, b1, xb4, N, 2, 0);
    k_aggrh<true><<<nb16 * 2, TB, 0, stream>>>(g4, offsets, csr_src, dinv, b1, xb4, N, 2, 2);
    // Layer 2: 128 -> 64  (MFMA fp16, fp16 blocked32 in; aggr writes fp16)
    k_mgemm<128, 64, true><<<nb128, 512, 0, stream>>>(xbuf, W2, dinv, gh, N);
    k_aggrh<true><<<nb16 * 2, TB, 0, stream>>>(g4, offsets, csr_src, dinv, b2, xb4, N, 2, 0);
    // Layer 3: 64 -> 32  (MFMA fp16, fp16 blocked32 in; aggr writes fp16
    //                     [n][32]h for the L4 VALU path)
    k_mgemm<64, 32, true><<<nb128, 512, 0, stream>>>(xbuf, W3, dinv, gh, N);
    k_aggrh<true><<<nb16 * 1, TB, 0, stream>>>(g4, offsets, csr_src, dinv, b3, xb4, N, 1, 0);
    // Layer 4: 32 -> 16  (VALU, fp16 [n][32]h in, fp16 [n][16]h out; fp16 aggr)
    k_gemm<32, 16, 4, 4><<<(N + 255) / 256, TB, 0, stream>>>(xbh, W4, dinv, gh, N);
    k_aggr16h<<<nb128, TB, 0, stream>>>(gh, offsets, csr_src, dinv, b4, xbh, N);
    // Layer 5: 16 -> 8  (VALU, fp16 [n][16]h in, fp16 [n][8]h out; aggr -> d_out)
    k_gemm<16, 8, 4, 4><<<(N + 511) / 512, TB, 0, stream>>>(xbh, W5, dinv, gh, N);
    k_aggr8h<<<nb256, TB, 0, stream>>>(gh, offsets, csr_src, dinv, b5, (float4*)out, N);
}

// Round 13
// 356.793 us; speedup vs baseline: 1.0594x; 1.0594x over previous
//
#include <hip/hip_runtime.h>
#include <hip/hip_bf16.h>
#include <hip/hip_fp16.h>

// 5-layer GCN: widths 128 -> 128/64/32/16/8, N=100000 nodes, E=1600000 edges.
// R23: FUSED NODE-LOCAL GEMMS — L4 (32->16) and L5 (16->8) GEMMs are
//      per-node linear maps; folded into the epilogues of aggrh-L3 (W4 via
//      8x16 partial + 2 shfl_xor rounds across the 4 node-lanes) and
//      aggr16h (W5 via 8x8 partial + 1 shfl_xor). Deletes both k_gemm
//      dispatches + ~19 MB of boundary round-trips; 15 -> 10 dispatches.
//      L1 diagnostic split reverted (R22 showed no kernel >40 us; top-5 is
//      harness workspace fills). Numerics: y feeds fused gemm in fp32
//      (skips one fp16 rounding) — strictly tighter.
// R20/21: fp16 L4/L5 tail. R19: fp16 layer boundaries.
// R18: bucket + LDS counting-sort CSR build. R17: MFMA fp16 GEMM L1-3.
// R15: fp16 gather payload, 32-feat slices (full-line gathers, at the
//      ~100 G line-touch/s device ceiling).

#define LDSE16  2048  // aggrh: staged edge indices (8 KB), 64 nodes/block
#define LDSE16B 3072  // aggr16h: staged edge indices (12 KB), 128 nodes/block
#define LDSE8H  6144  // aggr8h: staged edge indices (24 KB), 256 nodes/block
#define PCHUNK 4096   // k_bucket: edges per block
#define BNODES 512    // nodes per bucket
#define MAXBUK 256    // max buckets (N <= 131072)

typedef float floatx4 __attribute__((ext_vector_type(4)));
typedef _Float16 f16x4 __attribute__((ext_vector_type(4)));
typedef _Float16 f16x8 __attribute__((ext_vector_type(8)));

// ---------------- chunked bucket partition (bucket = dst/512) ----------------
__global__ __launch_bounds__(256) void k_bucket(const int* __restrict__ src,
                                                const int* __restrict__ dst,
                                                int2* __restrict__ pairs,
                                                int* __restrict__ bcnt,
                                                int E, int nbk, int CAP) {
    __shared__ int  hist[MAXBUK], pre[MAXBUK], cur[MAXBUK], gbase[MAXBUK], tmp[MAXBUK];
    __shared__ int2 arena[PCHUNK];              // 32 KB
    const int tid = threadIdx.x;
    const int e0  = blockIdx.x * PCHUNK;
    const int m   = (E - e0 < PCHUNK) ? (E - e0) : PCHUNK;

    hist[tid] = 0;
    __syncthreads();

    int dl[PCHUNK / 256], sl[PCHUNK / 256], rl[PCHUNK / 256];
#pragma unroll
    for (int j = 0; j < PCHUNK / 256; ++j) {
        int i = j * 256 + tid;
        rl[j] = -1;
        if (i < m) {
            dl[j] = __builtin_nontemporal_load(&dst[e0 + i]);
            sl[j] = __builtin_nontemporal_load(&src[e0 + i]);
            rl[j] = dl[j] >> 9;                 // dst / BNODES
            atomicAdd(&hist[rl[j]], 1);
        }
    }
    __syncthreads();
    // exclusive scan of hist[256]
    int v = hist[tid];
    tmp[tid] = v;
    __syncthreads();
    for (int off = 1; off < MAXBUK; off <<= 1) {
        int t = (tid >= off) ? tmp[tid - off] : 0;
        __syncthreads();
        tmp[tid] += t;
        __syncthreads();
    }
    pre[tid] = tmp[tid] - v;
    cur[tid] = 0;
    __syncthreads();
#pragma unroll
    for (int j = 0; j < PCHUNK / 256; ++j) {
        if (rl[j] >= 0) {
            int slot = pre[rl[j]] + atomicAdd(&cur[rl[j]], 1);
            arena[slot] = make_int2(dl[j], sl[j]);
        }
    }
    __syncthreads();
    if (tid < nbk && hist[tid] > 0) gbase[tid] = atomicAdd(&bcnt[tid], hist[tid]);
    __syncthreads();
    // flush: one wave per bucket, coalesced runs
    const int wave = tid >> 6, lane = tid & 63;
    for (int r = wave; r < nbk; r += 4) {
        int cnt = hist[r];
        if (cnt == 0) continue;
        int b0 = pre[r], g = gbase[r];
        for (int j = lane; j < cnt; j += 64)
            pairs[(size_t)r * CAP + g + j] = arena[b0 + j];
    }
}

// ---------------- per-bucket LDS counting sort -> CSR + deg/dinv/offsets ----
// Derives its own base via a 256-wide prefix of bcnt (bscan folded in).
__global__ __launch_bounds__(256) void k_sortfill(const int2* __restrict__ pairs,
                                                  const int* __restrict__ bcnt,
                                                  int* __restrict__ csr_src,
                                                  int* __restrict__ offsets,
                                                  float* __restrict__ dinv,
                                                  int n, int E, int nbk, int CAP) {
    __shared__ int hist[BNODES], lofs[BNODES], cur[BNODES], tmp[256];
    __shared__ int sbase;
    const int r    = blockIdx.x;
    const int tid  = threadIdx.x;
    const int node0 = r * BNODES;
    const int2* p = pairs + (size_t)r * CAP;

    // bucket-prefix: base = sum of bcnt[0..r-1]
    int bv = (tid < nbk) ? bcnt[tid] : 0;
    tmp[tid] = bv;
    __syncthreads();
    for (int off = 1; off < 256; off <<= 1) {
        int t = (tid >= off) ? tmp[tid - off] : 0;
        __syncthreads();
        tmp[tid] += t;
        __syncthreads();
    }
    if (tid == r) sbase = tmp[r] - bv;          // exclusive prefix at r
    if (r == nbk - 1 && tid == 0) offsets[n] = E;
    __syncthreads();
    const int m    = bcnt[r];
    const int base = sbase;

    for (int l = tid; l < BNODES; l += 256) hist[l] = 0;
    __syncthreads();
    for (int i = tid; i < m; i += 256)
        atomicAdd(&hist[p[i].x - node0], 1);
    __syncthreads();
    // exclusive scan of hist[512] with 256 threads (2 elems/thread)
    int a = hist[2 * tid], b = hist[2 * tid + 1];
    int s = a + b;
    tmp[tid] = s;
    __syncthreads();
    for (int off = 1; off < 256; off <<= 1) {
        int t = (tid >= off) ? tmp[tid - off] : 0;
        __syncthreads();
        tmp[tid] += t;
        __syncthreads();
    }
    int exc = tmp[tid] - s;
    lofs[2 * tid]     = exc;
    lofs[2 * tid + 1] = exc + a;
    cur[2 * tid] = 0;
    cur[2 * tid + 1] = 0;
    __syncthreads();
    // place: all global writes land in csr_src[base .. base+m) (32 KB window)
    for (int i = tid; i < m; i += 256) {
        int2 e = p[i];
        int l = e.x - node0;
        int pos = lofs[l] + atomicAdd(&cur[l], 1);
        csr_src[base + pos] = e.y;
    }
    for (int l = tid; l < BNODES; l += 256) {
        int node = node0 + l;
        if (node < n) {
            offsets[node] = base + lofs[l];
            dinv[node]    = rsqrtf((float)(hist[l] + 1));   // +1 self loop
        }
    }
}

// ---------------- MFMA fp16 GEMM (layers 1-3; fp16 blocked32 output) -------
// 512 threads = 4 waves; 128 nodes/block; wave w owns nodes 16w..16w+15.
// A staged fp16 LDS [node][k] pitch AP=KC+8; W^T staged fp16 [fo][k].
// H16IN: input fp16 blocked32 [fi/32][n][32]h; else fp32 row-major.
// mfma_f32_16x16x32_f16 frag: A row=lane&15, k=(lane>>4)*4+(r&3)+16*(r>>2);
// B col=lane&15 same k; D col=lane&15, row=(lane>>4)*4+r.
template <int FIN, int FOUT, bool H16IN>
__global__ __launch_bounds__(512) void k_mgemm(const float* __restrict__ x,
                                               const float* __restrict__ W,
                                               const float* __restrict__ dinv,
                                               _Float16* __restrict__ g, int n) {
    constexpr int KC  = (FIN < 64) ? FIN : 64;
    constexpr int NKQ = KC / 4;
    constexpr int AP  = KC + 8;              // pitch in halfs (16-B aligned rows)
    constexpr int NT  = FOUT / 16;
    __shared__ _Float16 As[128 * AP];
    __shared__ _Float16 Ws[FOUT * AP];
    __shared__ float dv[128];

    const int tid  = threadIdx.x;
    const int wave = tid >> 6;
    const int lane = tid & 63;
    const int m0   = blockIdx.x * 128;

    if (tid < 128) dv[tid] = (m0 + tid < n) ? dinv[m0 + tid] : 0.f;

    floatx4 acc[NT];
#pragma unroll
    for (int t = 0; t < NT; ++t) acc[t] = (floatx4)(0.f);

    for (int kc0 = 0; kc0 < FIN; kc0 += KC) {
        __syncthreads();
        if constexpr (H16IN) {
            const _Float16* xh = reinterpret_cast<const _Float16*>(x);
            constexpr int NC8 = KC / 8;
            for (int s = tid; s < 128 * NC8; s += 512) {
                int node = s / NC8, c8 = s % NC8;
                int gn = m0 + node, f0 = kc0 + c8 * 8;
                f16x8 h = (f16x8)(_Float16)0;
                if (gn < n)
                    h = *reinterpret_cast<const f16x8*>(
                        &xh[((size_t)(f0 >> 5) * n + gn) * 32 + (f0 & 31)]);
                *reinterpret_cast<f16x8*>(&As[node * AP + c8 * 8]) = h;
            }
        } else {
            const floatx4* x4 = reinterpret_cast<const floatx4*>(x);
            for (int s = tid; s < 128 * NKQ; s += 512) {
                int node = s / NKQ, kq = s % NKQ;
                int gn = m0 + node, gslot = kc0 / 4 + kq;
                floatx4 v = (floatx4)(0.f);
                if (gn < n)
                    v = __builtin_nontemporal_load(&x4[(size_t)gn * (FIN / 4) + gslot]);
                f16x4 h = {(_Float16)v.x, (_Float16)v.y, (_Float16)v.z, (_Float16)v.w};
                *reinterpret_cast<f16x4*>(&As[node * AP + kq * 4]) = h;
            }
        }
        // stage W^T: fp16 [fo][k]
        for (int s = tid; s < FOUT * NKQ; s += 512) {
            int fo = s % FOUT, kq = s / FOUT;
            int k = kc0 + kq * 4;
            f16x4 h = {(_Float16)W[(k + 0) * FOUT + fo], (_Float16)W[(k + 1) * FOUT + fo],
                       (_Float16)W[(k + 2) * FOUT + fo], (_Float16)W[(k + 3) * FOUT + fo]};
            *reinterpret_cast<f16x4*>(&Ws[fo * AP + kq * 4]) = h;
        }
        __syncthreads();
#pragma unroll
        for (int kk = 0; kk < KC / 32; ++kk) {
            const int ka = kk * 32 + ((lane >> 4) << 2);
            const _Float16* ap = &As[(wave * 16 + (lane & 15)) * AP + ka];
            f16x4 alo = *reinterpret_cast<const f16x4*>(ap);
            f16x4 ahi = *reinterpret_cast<const f16x4*>(ap + 16);
            f16x8 a = {alo[0], alo[1], alo[2], alo[3], ahi[0], ahi[1], ahi[2], ahi[3]};
#pragma unroll
            for (int t = 0; t < NT; ++t) {
                const _Float16* bp = &Ws[(t * 16 + (lane & 15)) * AP + ka];
                f16x4 blo = *reinterpret_cast<const f16x4*>(bp);
                f16x4 bhi = *reinterpret_cast<const f16x4*>(bp + 16);
                f16x8 b = {blo[0], blo[1], blo[2], blo[3], bhi[0], bhi[1], bhi[2], bhi[3]};
                acc[t] = __builtin_amdgcn_mfma_f32_16x16x32_f16(a, b, acc[t], 0, 0, 0);
            }
        }
    }

    const int i0 = (lane >> 4) << 2;
#pragma unroll
    for (int r = 0; r < 4; ++r) {
        int nl = wave * 16 + i0 + r;
        int node = m0 + nl;
        if (node < n) {
            float d = dv[nl];
#pragma unroll
            for (int t = 0; t < NT; ++t) {
                int fo = t * 16 + (lane & 15);
                g[((size_t)(fo >> 5) * n + node) * 32 + (fo & 31)] = (_Float16)(acc[t][r] * d);
            }
        }
    }
}

// accumulate 8 fp16 feats (one float4 = 4 half2) into 8 fp32 accumulators
#define ACCUM8(A, v) {                                                        \
    union { float4 f; __half2 h[4]; } u_; u_.f = (v);                         \
    _Pragma("unroll")                                                         \
    for (int j_ = 0; j_ < 4; ++j_) {                                          \
        float2 f_ = __half22float2(u_.h[j_]);                                 \
        A[2 * j_] += f_.x; A[2 * j_ + 1] += f_.y;                             \
    } }

// ---------------- fp16 32-feat-slice CSR aggregation (layers 1-3) ----------
// g fp16 blocked32 [f/32][N][32]h: 64 B/node/slice, 4 lanes/node, 8 loads in
// flight. fp32 accumulation.
// FUSE==0:  write y as fp16 blocked32 [sl][n][32]h.
// FUSE==16: (L3 only, nsl==1) fused next-layer GEMM — z = (y @ Wn) * dnode,
//           via per-lane 8x16 partial + shfl_xor(1)+shfl_xor(2) over the 4
//           node-lanes; writes fp16 row-major [n][16]h.
template <int FUSE>
__global__ __launch_bounds__(256) void k_aggrh(const float4* __restrict__ gh,
                                               const int* __restrict__ offsets,
                                               const int* __restrict__ csr_src,
                                               const float* __restrict__ dinv,
                                               const float* __restrict__ bias,
                                               const float* __restrict__ Wn,
                                               _Float16* __restrict__ outh,
                                               int n, int nsl) {
    __shared__ int eidx[LDSE16];
    __shared__ float Wl[(FUSE > 0) ? 32 * FUSE : 1];
    const int sl     = blockIdx.x % nsl;
    const int nb     = blockIdx.x / nsl;
    const int node0  = nb * 64;
    const int nodeHi = (node0 + 64 < n) ? node0 + 64 : n;
    const int node   = node0 + (threadIdx.x >> 2);
    const int q      = threadIdx.x & 3;

    const int eS = offsets[node0];
    const int eE = offsets[nodeHi];
    const int C  = eE - eS;
    const bool useLds = (C <= LDSE16);

    const bool alive = (node < n);
    int e0 = 0, e1 = 0;
    float dnode = 0.f;
    const float4* gs = gh + (size_t)sl * n * 4;   // 4 float4 (64 B) per node
    float A[8], B[8];
#pragma unroll
    for (int j = 0; j < 8; ++j) { A[j] = 0.f; B[j] = 0.f; }
    if (alive) {
        e0 = offsets[node];
        e1 = offsets[node + 1];
        dnode = dinv[node];
        float4 vs = gs[(size_t)node * 4 + q];     // self-loop term
        ACCUM8(A, vs);
    }

    if constexpr (FUSE > 0) {
        for (int i = threadIdx.x; i < 32 * FUSE; i += 256) Wl[i] = Wn[i];
    }
    if (useLds) {
        for (int i = threadIdx.x; i < C; i += 256)
            eidx[i] = __builtin_nontemporal_load(&csr_src[eS + i]);
    }
    __syncthreads();
    if (!alive) return;

    const int m = e1 - e0;
    int i = 0;
    if (useLds) {
        const int le = e0 - eS;
        for (; i + 8 <= m; i += 8) {
            int s0 = eidx[le + i + 0], s1 = eidx[le + i + 1];
            int s2 = eidx[le + i + 2], s3 = eidx[le + i + 3];
            int s4 = eidx[le + i + 4], s5 = eidx[le + i + 5];
            int s6 = eidx[le + i + 6], s7 = eidx[le + i + 7];
            float4 v0 = gs[(size_t)s0 * 4 + q], v1 = gs[(size_t)s1 * 4 + q];
            float4 v2 = gs[(size_t)s2 * 4 + q], v3 = gs[(size_t)s3 * 4 + q];
            float4 v4 = gs[(size_t)s4 * 4 + q], v5 = gs[(size_t)s5 * 4 + q];
            float4 v6 = gs[(size_t)s6 * 4 + q], v7 = gs[(size_t)s7 * 4 + q];
            ACCUM8(A, v0); ACCUM8(B, v1); ACCUM8(A, v2); ACCUM8(B, v3);
            ACCUM8(A, v4); ACCUM8(B, v5); ACCUM8(A, v6); ACCUM8(B, v7);
        }
        for (; i + 4 <= m; i += 4) {
            int s0 = eidx[le + i + 0], s1 = eidx[le + i + 1];
            int s2 = eidx[le + i + 2], s3 = eidx[le + i + 3];
            float4 v0 = gs[(size_t)s0 * 4 + q], v1 = gs[(size_t)s1 * 4 + q];
            float4 v2 = gs[(size_t)s2 * 4 + q], v3 = gs[(size_t)s3 * 4 + q];
            ACCUM8(A, v0); ACCUM8(B, v1); ACCUM8(A, v2); ACCUM8(B, v3);
        }
        for (; i < m; ++i) {
            float4 v = gs[(size_t)eidx[le + i] * 4 + q];
            ACCUM8(A, v);
        }
    } else {
        for (; i + 4 <= m; i += 4) {
            int s0 = csr_src[e0 + i + 0], s1 = csr_src[e0 + i + 1];
            int s2 = csr_src[e0 + i + 2], s3 = csr_src[e0 + i + 3];
            float4 v0 = gs[(size_t)s0 * 4 + q], v1 = gs[(size_t)s1 * 4 + q];
            float4 v2 = gs[(size_t)s2 * 4 + q], v3 = gs[(size_t)s3 * 4 + q];
            ACCUM8(A, v0); ACCUM8(B, v1); ACCUM8(A, v2); ACCUM8(B, v3);
        }
        for (; i < m; ++i) {
            float4 v = gs[(size_t)csr_src[e0 + i] * 4 + q];
            ACCUM8(A, v);
        }
    }

    const float* bf = bias + sl * 32 + q * 8;
    float r[8];
#pragma unroll
    for (int j = 0; j < 8; ++j)
        r[j] = fmaxf(dnode * (A[j] + B[j]) + bf[j], 0.f);

    if constexpr (FUSE == 16) {
        // fused next-layer GEMM: z = (y @ Wn[32][16]) * dnode
        float p[16];
#pragma unroll
        for (int f = 0; f < 16; ++f) p[f] = 0.f;
#pragma unroll
        for (int j = 0; j < 8; ++j) {
            float rv = r[j];
            const float* wr = &Wl[(q * 8 + j) * 16];
#pragma unroll
            for (int f = 0; f < 16; ++f) p[f] += rv * wr[f];
        }
#pragma unroll
        for (int f = 0; f < 16; ++f) {
            p[f] += __shfl_xor(p[f], 1);
            p[f] += __shfl_xor(p[f], 2);
        }
        f16x4 o;
#pragma unroll
        for (int t = 0; t < 4; ++t) o[t] = (_Float16)(p[q * 4 + t] * dnode);
        *reinterpret_cast<f16x4*>(&outh[(size_t)node * 16 + q * 4]) = o;
    } else {
        f16x8 o;
#pragma unroll
        for (int j = 0; j < 8; ++j) o[j] = (_Float16)r[j];
        __builtin_nontemporal_store(
            o, reinterpret_cast<f16x8*>(&outh[((size_t)sl * n + node) * 32 + q * 8]));
    }
}

// ---------------- fp16 16-feat CSR aggregation + fused L5 GEMM (layer 4) ---
// g fp16 row-major [n][16]h (32 B/node); 2 lanes/node, 128 nodes/block.
// fp32 accumulation; fused z = (y @ Wn[16][8]) * dnode via per-lane 8x8
// partial + shfl_xor(1); writes fp16 row-major [n][8]h.
__global__ __launch_bounds__(256) void k_aggr16h(const _Float16* __restrict__ gh,
                                                 const int* __restrict__ offsets,
                                                 const int* __restrict__ csr_src,
                                                 const float* __restrict__ dinv,
                                                 const float* __restrict__ bias,
                                                 const float* __restrict__ Wn,
                                                 _Float16* __restrict__ outh, int n) {
    __shared__ int eidx[LDSE16B];
    __shared__ float Wl[16 * 8];
    const int node0  = blockIdx.x * 128;
    const int nodeHi = (node0 + 128 < n) ? node0 + 128 : n;
    const int node   = node0 + (threadIdx.x >> 1);
    const int h      = threadIdx.x & 1;

    const int eS = offsets[node0];
    const int eE = offsets[nodeHi];
    const int C  = eE - eS;
    const bool useLds = (C <= LDSE16B);

    const bool alive = (node < n);
    int e0 = 0, e1 = 0;
    float dnode = 0.f;
    float A[8], B[8];
#pragma unroll
    for (int j = 0; j < 8; ++j) { A[j] = 0.f; B[j] = 0.f; }
    if (alive) {
        e0 = offsets[node];
        e1 = offsets[node + 1];
        dnode = dinv[node];
        f16x8 vs = *reinterpret_cast<const f16x8*>(&gh[(size_t)node * 16 + h * 8]);
#pragma unroll
        for (int j = 0; j < 8; ++j) A[j] += (float)vs[j];
    }

    if (threadIdx.x < 128) Wl[threadIdx.x] = Wn[threadIdx.x];
    if (useLds) {
        for (int i = threadIdx.x; i < C; i += 256)
            eidx[i] = __builtin_nontemporal_load(&csr_src[eS + i]);
    }
    __syncthreads();
    if (!alive) return;

    const int m = e1 - e0;
    int i = 0;
    if (useLds) {
        const int le = e0 - eS;
        for (; i + 4 <= m; i += 4) {
            int s0 = eidx[le + i + 0], s1 = eidx[le + i + 1];
            int s2 = eidx[le + i + 2], s3 = eidx[le + i + 3];
            f16x8 v0 = *reinterpret_cast<const f16x8*>(&gh[(size_t)s0 * 16 + h * 8]);
            f16x8 v1 = *reinterpret_cast<const f16x8*>(&gh[(size_t)s1 * 16 + h * 8]);
            f16x8 v2 = *reinterpret_cast<const f16x8*>(&gh[(size_t)s2 * 16 + h * 8]);
            f16x8 v3 = *reinterpret_cast<const f16x8*>(&gh[(size_t)s3 * 16 + h * 8]);
#pragma unroll
            for (int j = 0; j < 8; ++j) {
                A[j] += (float)v0[j] + (float)v2[j];
                B[j] += (float)v1[j] + (float)v3[j];
            }
        }
        for (; i < m; ++i) {
            f16x8 v = *reinterpret_cast<const f16x8*>(
                &gh[(size_t)eidx[le + i] * 16 + h * 8]);
#pragma unroll
            for (int j = 0; j < 8; ++j) A[j] += (float)v[j];
        }
    } else {
        for (; i < m; ++i) {
            f16x8 v = *reinterpret_cast<const f16x8*>(
                &gh[(size_t)csr_src[e0 + i] * 16 + h * 8]);
#pragma unroll
            for (int j = 0; j < 8; ++j) A[j] += (float)v[j];
        }
    }

    const float* bf = bias + h * 8;
    float r[8];
#pragma unroll
    for (int j = 0; j < 8; ++j)
        r[j] = fmaxf(dnode * (A[j] + B[j]) + bf[j], 0.f);

    // fused L5 GEMM: z = (y @ Wn[16][8]) * dnode
    float p[8];
#pragma unroll
    for (int f = 0; f < 8; ++f) p[f] = 0.f;
#pragma unroll
    for (int j = 0; j < 8; ++j) {
        float rv = r[j];
        const float* wr = &Wl[(h * 8 + j) * 8];
#pragma unroll
        for (int f = 0; f < 8; ++f) p[f] += rv * wr[f];
    }
#pragma unroll
    for (int f = 0; f < 8; ++f) p[f] += __shfl_xor(p[f], 1);
    f16x4 o;
#pragma unroll
    for (int t = 0; t < 4; ++t) o[t] = (_Float16)(p[h * 4 + t] * dnode);
    *reinterpret_cast<f16x4*>(&outh[(size_t)node * 8 + h * 4]) = o;
}

// ---------------- fp16 8-feat CSR aggregation (layer 5, writes d_out) ------
// g fp16 row-major [n][8]h (16 B/node); 1 lane/node (one f16x8 per edge),
// 256 nodes/block. fp32 accumulation; writes fp32 [n][8] d_out.
__global__ __launch_bounds__(256) void k_aggr8h(const _Float16* __restrict__ gh,
                                                const int* __restrict__ offsets,
                                                const int* __restrict__ csr_src,
                                                const float* __restrict__ dinv,
                                                const float* __restrict__ bias,
                                                float4* __restrict__ outb, int n) {
    __shared__ int eidx[LDSE8H];
    const int node0  = blockIdx.x * 256;
    const int nodeHi = (node0 + 256 < n) ? node0 + 256 : n;
    const int node   = node0 + threadIdx.x;

    const int eS = offsets[node0];
    const int eE = offsets[nodeHi];
    const int C  = eE - eS;
    const bool useLds = (C <= LDSE8H);

    const bool alive = (node < n);
    int e0 = 0, e1 = 0;
    float dnode = 0.f;
    float A[8], B[8];
#pragma unroll
    for (int j = 0; j < 8; ++j) { A[j] = 0.f; B[j] = 0.f; }
    if (alive) {
        e0 = offsets[node];
        e1 = offsets[node + 1];
        dnode = dinv[node];
        f16x8 vs = *reinterpret_cast<const f16x8*>(&gh[(size_t)node * 8]);
#pragma unroll
        for (int j = 0; j < 8; ++j) A[j] += (float)vs[j];
    }

    if (useLds) {
        for (int i = threadIdx.x; i < C; i += 256)
            eidx[i] = __builtin_nontemporal_load(&csr_src[eS + i]);
    }
    __syncthreads();
    if (!alive) return;

    const int m = e1 - e0;
    int i = 0;
    if (useLds) {
        const int le = e0 - eS;
        for (; i + 4 <= m; i += 4) {
            int s0 = eidx[le + i + 0], s1 = eidx[le + i + 1];
            int s2 = eidx[le + i + 2], s3 = eidx[le + i + 3];
            f16x8 v0 = *reinterpret_cast<const f16x8*>(&gh[(size_t)s0 * 8]);
            f16x8 v1 = *reinterpret_cast<const f16x8*>(&gh[(size_t)s1 * 8]);
            f16x8 v2 = *reinterpret_cast<const f16x8*>(&gh[(size_t)s2 * 8]);
            f16x8 v3 = *reinterpret_cast<const f16x8*>(&gh[(size_t)s3 * 8]);
#pragma unroll
            for (int j = 0; j < 8; ++j) {
                A[j] += (float)v0[j] + (float)v2[j];
                B[j] += (float)v1[j] + (float)v3[j];
            }
        }
        for (; i < m; ++i) {
            f16x8 v = *reinterpret_cast<const f16x8*>(&gh[(size_t)eidx[le + i] * 8]);
#pragma unroll
            for (int j = 0; j < 8; ++j) A[j] += (float)v[j];
        }
    } else {
        for (; i < m; ++i) {
            f16x8 v = *reinterpret_cast<const f16x8*>(&gh[(size_t)csr_src[e0 + i] * 8]);
#pragma unroll
            for (int j = 0; j < 8; ++j) A[j] += (float)v[j];
        }
    }

    floatx4 r0, r1;
    r0.x = fmaxf(dnode * (A[0] + B[0]) + bias[0], 0.f);
    r0.y = fmaxf(dnode * (A[1] + B[1]) + bias[1], 0.f);
    r0.z = fmaxf(dnode * (A[2] + B[2]) + bias[2], 0.f);
    r0.w = fmaxf(dnode * (A[3] + B[3]) + bias[3], 0.f);
    r1.x = fmaxf(dnode * (A[4] + B[4]) + bias[4], 0.f);
    r1.y = fmaxf(dnode * (A[5] + B[5]) + bias[5], 0.f);
    r1.z = fmaxf(dnode * (A[6] + B[6]) + bias[6], 0.f);
    r1.w = fmaxf(dnode * (A[7] + B[7]) + bias[7], 0.f);
    floatx4* ob = reinterpret_cast<floatx4*>(outb);
    __builtin_nontemporal_store(r0, &ob[(size_t)node * 2 + 0]);
    __builtin_nontemporal_store(r1, &ob[(size_t)node * 2 + 1]);
}

extern "C" void kernel_launch(void* const* d_in, const int* in_sizes, int n_in,
                              void* d_out, int out_size, void* d_ws, size_t ws_size,
                              hipStream_t stream) {
    const int N = in_sizes[0] / 128;
    const int E = in_sizes[1] / 2;
    const int nbk = (N + BNODES - 1) / BNODES;            // 196 buckets
    const int avg = (E + nbk - 1) / nbk;
    const int CAP = avg + avg / 4 + 512;                  // ~11+ sigma headroom

    const float* x   = (const float*)d_in[0];
    const int*   ei  = (const int*)d_in[1];
    const int*   src = ei;
    const int*   dst = ei + E;
    const float* W1 = (const float*)d_in[2],  *b1 = (const float*)d_in[3];
    const float* W2 = (const float*)d_in[4],  *b2 = (const float*)d_in[5];
    const float* W3 = (const float*)d_in[6],  *b3 = (const float*)d_in[7];
    const float* W4 = (const float*)d_in[8],  *b4 = (const float*)d_in[9];
    const float* W5 = (const float*)d_in[10], *b5 = (const float*)d_in[11];
    float* out = (float*)d_out;

    size_t off = 0;
    auto alloc = [&](size_t bytes) {
        void* p = (char*)d_ws + off;
        off += (bytes + 255) & ~(size_t)255;
        return p;
    };
    int*   offsets = (int*)alloc((size_t)(N + 1) * 4);
    float* dinv    = (float*)alloc((size_t)N * 4);
    int*   csr_src = (int*)alloc((size_t)E * 4);
    int*   bcnt    = (int*)alloc(MAXBUK * 4);
    int2*  pairs   = (int2*)alloc((size_t)nbk * CAP * 8);
    float* g       = (float*)alloc((size_t)N * 128 * 4);
    float* xbuf    = (float*)alloc((size_t)N * 128 * 4);

    (void)hipMemsetAsync(bcnt, 0, MAXBUK * 4, stream);

    const int TB = 256;
    int nb16  = (N + 63) / 64;       // aggrh: 64 nodes per block
    int nb128 = (N + 127) / 128;     // aggr16h / mgemm: 128 nodes per block
    int nb256 = (N + 255) / 256;     // aggr8h: 256 nodes per block
    int nch   = (E + PCHUNK - 1) / PCHUNK;

    k_bucket<<<nch, TB, 0, stream>>>(src, dst, pairs, bcnt, E, nbk, CAP);
    k_sortfill<<<nbk, TB, 0, stream>>>(pairs, bcnt, csr_src, offsets, dinv, N, E, nbk, CAP);

    const float4* g4  = (const float4*)g;
    const float4* xb4 = (const float4*)xbuf;
    _Float16*     gh  = (_Float16*)g;
    _Float16*     xbh = (_Float16*)xbuf;

    // Layer 1: 128 -> 128  (MFMA fp16, fp32 row-major in; fp16 g, 4 slice32s)
    k_mgemm<128, 128, false><<<nb128, 512, 0, stream>>>(x, W1, dinv, gh, N);
    k_aggrh<0><<<nb16 * 4, TB, 0, stream>>>(g4, offsets, csr_src, dinv, b1, nullptr, xbh, N, 4);
    // Layer 2: 128 -> 64  (MFMA fp16, fp16 blocked32 in)
    k_mgemm<128, 64, true><<<nb128, 512, 0, stream>>>(xbuf, W2, dinv, gh, N);
    k_aggrh<0><<<nb16 * 2, TB, 0, stream>>>(g4, offsets, csr_src, dinv, b2, nullptr, xbh, N, 2);
    // Layer 3: 64 -> 32  (MFMA fp16; aggr FUSES the L4 GEMM (W4) -> [n][16]h)
    k_mgemm<64, 32, true><<<nb128, 512, 0, stream>>>(xbuf, W3, dinv, gh, N);
    k_aggrh<16><<<nb16 * 1, TB, 0, stream>>>(g4, offsets, csr_src, dinv, b3, W4, xbh, N, 1);
    // Layer 4 aggr + fused L5 GEMM (W5): [n][16]h -> [n][8]h
    k_aggr16h<<<nb128, TB, 0, stream>>>(xbh, offsets, csr_src, dinv, b4, W5, gh, N);
    // Layer 5 aggr: [n][8]h -> fp32 d_out
    k_aggr8h<<<nb256, TB, 0, stream>>>(gh, offsets, csr_src, dinv, b5, (float4*)out, N);
}